// Round 8
// baseline (1549.389 us; speedup 1.0000x reference)
//
#include <hip/hip_runtime.h>
#include <hip/hip_bf16.h>

#define TDIM 2048
#define FDIM 128
#define NWAVES 8

typedef __attribute__((ext_vector_type(8))) short short8;
typedef __attribute__((ext_vector_type(4))) float f32x4;
typedef __attribute__((ext_vector_type(4))) unsigned uint4v;

__device__ __forceinline__ unsigned short f2bf(float v) {
    __bf16 h = (__bf16)v;
    return __builtin_bit_cast(unsigned short, h);
}

// ---------------- weight prep -> bf16 in d_ws ----------------
//  wt1 @ 0     : [2 cot][4 kb][16 co][8 e]   k=kb*8+e, uv=k>>1, ch=k&1; 0 for k>=18   1024
//  wt2 @ 1024  : [4 g][9 uv][32 co][8 ci]                                             9216
//  wt3 @ 10240 : [4 g][9 uv][32 co][8 ci]                                             9216
//  wt4 @ 19456 : [4 g][9 uv][16 co][8 ci]  (co>0 zero)                                4608
__global__ void prep_weights_kernel(const float* __restrict__ W1, const float* __restrict__ W2,
                                    const float* __restrict__ W3, const float* __restrict__ W4,
                                    unsigned short* __restrict__ wt)
{
    for (int e = blockIdx.x * 256 + threadIdx.x; e < 24064; e += gridDim.x * 256) {
        float v = 0.0f;
        if (e < 1024) {
            int cot = e >> 9, kb = (e >> 7) & 3, co16 = (e >> 3) & 15, ee = e & 7;
            int k = kb * 8 + ee, uv = k >> 1, ch = k & 1, co = cot * 16 + co16;
            if (uv < 9) v = W1[co * 18 + ch * 9 + uv];
        } else if (e < 10240) {
            int q = e - 1024;
            int g = q / 2304, r = q % 2304;
            int uv = r >> 8, co = (r >> 3) & 31, ci = g * 8 + (r & 7);
            v = W2[co * 288 + ci * 9 + uv];
        } else if (e < 19456) {
            int q = e - 10240;
            int g = q / 2304, r = q % 2304;
            int uv = r >> 8, co = (r >> 3) & 31, ci = g * 8 + (r & 7);
            v = W3[co * 288 + ci * 9 + uv];
        } else {
            int q = e - 19456;
            int g = q / 1152, r = q % 1152;
            int uv = r >> 7, co = (r >> 3) & 15, ci = g * 8 + (r & 7);
            if (co == 0) v = W4[ci * 9 + uv];
        }
        wt[e] = f2bf(v);
    }
}

__device__ __forceinline__ uint2 pack4(f32x4 c, bool valid) {
    unsigned short h[4];
#pragma unroll
    for (int k = 0; k < 4; ++k) {
        float v = fmaxf(c[k], 0.0f);
        h[k] = valid ? f2bf(v) : (unsigned short)0;
    }
    uint2 r;
    r.x = (unsigned)h[0] | ((unsigned)h[1] << 16);
    r.y = (unsigned)h[2] | ((unsigned)h[3] << 16);
    return r;
}

// Generic panel conv: in planes [4][.. WI cols][16B] -> out planes [4][.. WO cols][16B]
// weights from global: [4 g][9 uv][32 co][8 ci]
// in row  = in_off  + r (+u);  out row = out_off + r;  r = local row index over npx=WO*nrows
template<int WI, int WO, int PSI, int PSO>
__device__ __forceinline__ void conv_panel(const char* __restrict__ inb, char* __restrict__ outb,
                                           const unsigned short* __restrict__ wg,
                                           const float* __restrict__ bias,
                                           int wave, int lane, int tvb, int f_base,
                                           int in_off, int out_off, int npx, bool edge)
{
    const int lm = lane & 15, g = lane >> 4;
    const unsigned short* wp = wg + g * 2304 + lm * 8;
    short8 wa0[9], wa1[9];
#pragma unroll
    for (int uv = 0; uv < 9; ++uv) {
        wa0[uv] = *(const short8*)(wp + uv * 256);
        wa1[uv] = *(const short8*)(wp + uv * 256 + 128);
    }
    f32x4 bias0 = *(const f32x4*)(bias + g * 4);
    f32x4 bias1 = *(const f32x4*)(bias + 16 + g * 4);
    const f32x4 zero = {0.0f, 0.0f, 0.0f, 0.0f};

    const char* inp = inb + g * PSI;
    const int NG = (npx + 15) >> 4;
    for (int grp = wave; grp < NG; grp += NWAVES) {
        int m = grp * 16 + lm;
        bool mv = m < npx;
        int mc = mv ? m : npx - 1;
        int r = mc / WO, j = mc - r * WO;
        const char* base = inp + ((in_off + r) * WI + j) * 16;
        f32x4 c0a = bias0, c0b = zero, c1a = bias1, c1b = zero;
#pragma unroll
        for (int uv = 0; uv < 9; ++uv) {
            int u = uv / 3, v = uv - u * 3;
            short8 bf = *(const short8*)(base + (u * WI + v) * 16);
            if (uv < 5) {
                c0a = __builtin_amdgcn_mfma_f32_16x16x32_bf16(wa0[uv], bf, c0a, 0, 0, 0);
                c1a = __builtin_amdgcn_mfma_f32_16x16x32_bf16(wa1[uv], bf, c1a, 0, 0, 0);
            } else {
                c0b = __builtin_amdgcn_mfma_f32_16x16x32_bf16(wa0[uv], bf, c0b, 0, 0, 0);
                c1b = __builtin_amdgcn_mfma_f32_16x16x32_bf16(wa1[uv], bf, c1b, 0, 0, 0);
            }
        }
        if (mv) {
            char* wb = outb + (g >> 1) * PSO + ((out_off + r) * WO + j) * 16 + (g & 1) * 8;
            if (edge) {
                int t = tvb + r, f = f_base + j;
                bool valid = (t >= 0) && (t < TDIM) && (f >= 0) && (f < FDIM);
                *(uint2*)wb             = pack4(c0a + c0b, valid);
                *(uint2*)(wb + 2 * PSO) = pack4(c1a + c1b, valid);
            } else {
                *(uint2*)wb             = pack4(c0a + c0b, true);
                *(uint2*)(wb + 2 * PSO) = pack4(c1a + c1b, true);
            }
        }
    }
}

// conv1 panel: X4 [24x24 px][4B] -> P planes [4][9*22][16B] (plane stride 3168)
// Y1 storage row gi = obase + i_local; K=32 packed (k=uv*2+ch)
__device__ __forceinline__ void conv1_panel(const unsigned* __restrict__ X4, char* __restrict__ P,
                                            const unsigned short* __restrict__ wt,
                                            const float* __restrict__ b1,
                                            int wave, int lane, int t0, int f0,
                                            int obase, int nrows, bool edge)
{
    const int lm = lane & 15, g = lane >> 4;
    const char* wtb = (const char*)wt;
    const short8 waA = *(const short8*)(wtb + (g * 16 + lm) * 16);
    const short8 waB = *(const short8*)(wtb + (64 + g * 16 + lm) * 16);
    int off4[4];
#pragma unroll
    for (int q = 0; q < 4; ++q) {
        int uv = g * 4 + q;
        int uvc = uv <= 8 ? uv : 8;      // weights zero beyond uv=8; clamp address only
        int u = uvc / 3, v = uvc - u * 3;
        off4[q] = u * 24 + v;
    }
    f32x4 bias0 = *(const f32x4*)(b1 + g * 4);
    f32x4 bias1 = *(const f32x4*)(b1 + 16 + g * 4);

    const int npx = nrows * 22;
    const int NG = (npx + 15) >> 4;
    for (int grp = wave; grp < NG; grp += NWAVES) {
        int m = grp * 16 + lm;
        bool mv = m < npx;
        int mc = mv ? m : npx - 1;
        int i = mc / 22, j = mc - i * 22;
        int gi = obase + i;
        int base4 = gi * 24 + j;
        uint4v bu;
#pragma unroll
        for (int q = 0; q < 4; ++q) bu[q] = X4[base4 + off4[q]];
        short8 bf = __builtin_bit_cast(short8, bu);
        f32x4 c0 = __builtin_amdgcn_mfma_f32_16x16x32_bf16(waA, bf, bias0, 0, 0, 0);
        f32x4 c1 = __builtin_amdgcn_mfma_f32_16x16x32_bf16(waB, bf, bias1, 0, 0, 0);
        if (mv) {
            char* wb = P + (g >> 1) * 3168 + (i * 22 + j) * 16 + (g & 1) * 8;
            if (edge) {
                int t = t0 - 3 + gi, f = f0 - 3 + j;
                bool valid = (t >= 0) && (t < TDIM) && (f >= 0) && (f < FDIM);
                *(uint2*)wb          = pack4(c0, valid);
                *(uint2*)(wb + 6336) = pack4(c1, valid);
            } else {
                *(uint2*)wb          = pack4(c0, true);
                *(uint2*)(wb + 6336) = pack4(c1, true);
            }
        }
    }
}

// conv4 panel: P = Y3 panel planes [4][..18 cols][16B] (plane stride 3168) -> out fp32
// out row = t0 + obase + grp; local Y3 row = lbase + grp + u
__device__ __forceinline__ void conv4_panel(const char* __restrict__ P,
                                            const unsigned short* __restrict__ wt,
                                            const float* __restrict__ b4, float* __restrict__ out,
                                            int wave, int lane, int b, int t0, int f0,
                                            int obase, int lbase)
{
    const int lm = lane & 15, g = lane >> 4;
    const unsigned short* wp = wt + 19456 + g * 1152 + lm * 8;
    short8 wa[9];
#pragma unroll
    for (int uv = 0; uv < 9; ++uv)
        wa[uv] = *(const short8*)(wp + uv * 128);
    float bv = b4[0];
    const char* yp = P + g * 3168;
    const f32x4 zero = {0.0f, 0.0f, 0.0f, 0.0f};
    for (int grp = wave; grp < 8; grp += NWAVES) {
        const char* base = yp + ((lbase + grp) * 18 + lm) * 16;
        f32x4 ca = zero, cb = zero;
#pragma unroll
        for (int uv = 0; uv < 9; ++uv) {
            int u = uv / 3, v = uv - u * 3;
            short8 bf = *(const short8*)(base + (u * 18 + v) * 16);
            if (uv < 5) ca = __builtin_amdgcn_mfma_f32_16x16x32_bf16(wa[uv], bf, ca, 0, 0, 0);
            else        cb = __builtin_amdgcn_mfma_f32_16x16x32_bf16(wa[uv], bf, cb, 0, 0, 0);
        }
        if (g == 0)
            out[((long)b * TDIM + (t0 + obase + grp)) * FDIM + f0 + lm] = ca[0] + cb[0] + bv;
    }
}

// LDS (bytes), total 40576 -> 4 blocks/CU:
//  X4 [0, 2304)      : [576 px][4B]      live through conv1 sub-phase c
//  Y2 [2304, 27904)  : planes [4][400][16]
//  P  [27904, 40576) : 12672B shared panel: Y1 thirds [4][9*22][16] / Y3 halves [4][11*18][16]
__global__ __launch_bounds__(512, 8)
void fused_mfma_kernel(const float* __restrict__ pr, const float* __restrict__ onset,
                       const int* __restrict__ tf,
                       const float* __restrict__ b1, const float* __restrict__ b2,
                       const float* __restrict__ b3, const float* __restrict__ b4,
                       const unsigned short* __restrict__ wt, float* __restrict__ out)
{
    __shared__ __attribute__((aligned(16))) char lds[40576];

    const int tid = threadIdx.x;
    const int lane = tid & 63, wave = tid >> 6;
    const int f0 = blockIdx.x * 16;
    const int t0 = blockIdx.y * 16;
    const int b  = blockIdx.z;
    const bool edge = (blockIdx.x == 0) || (blockIdx.x == 7) ||
                      (blockIdx.y == 0) || (blockIdx.y == 127);

    unsigned* X4 = (unsigned*)lds;
    char* Y2 = lds + 2304;
    char* P  = lds + 27904;

    // ---- stage X4 [24][24] with per-pixel branchless tatum search ----
    for (int p = tid; p < 576; p += 512) {
        int i = p / 24, j = p - (p / 24) * 24;
        int t = t0 - 4 + i, f = f0 - 4 + j;
        unsigned xv = 0u;
        bool valid = true;
        if (edge) valid = (t >= 0) && (t < TDIM) && (f >= 0) && (f < FDIM);
        if (valid) {
            const int* a = tf + b * 257 + 1;
            int pos = 0;
#pragma unroll
            for (int step = 128; step >= 1; step >>= 1) {
                pos += (a[pos + step - 1] <= t) ? step : 0;   // max idx 254
            }
            int idx = pos < 255 ? pos : 255;
            float v0 = pr[(b * 256 + idx) * 128 + f];
            float v1 = onset[b * 256 + idx];
            xv = (unsigned)f2bf(v0) | ((unsigned)f2bf(v1) << 16);
        }
        X4[p] = xv;
    }
    __syncthreads();

    // ---- conv1/conv2 streamed in thirds over t-rows ----
    // sub s: conv1 Y1 storage rows [c1o, c1o+c1n) -> P; conv2 out rows [c2o, c2o+c2n)
    //   s0: c1o=0  c1n=9  | c2o=0  c2n=7
    //   s1: c1o=7  c1n=9  | c2o=7  c2n=7
    //   s2: c1o=14 c1n=8  | c2o=14 c2n=6
    conv1_panel(X4, P, wt, b1, wave, lane, t0, f0, 0, 9, edge);
    __syncthreads();
    conv_panel<22, 20, 3168, 6400>(P, Y2, wt + 1024, b2, wave, lane,
                                   t0 - 2 + 0, f0 - 2, 0, 0, 7 * 20, edge);
    __syncthreads();
    conv1_panel(X4, P, wt, b1, wave, lane, t0, f0, 7, 9, edge);
    __syncthreads();
    conv_panel<22, 20, 3168, 6400>(P, Y2, wt + 1024, b2, wave, lane,
                                   t0 - 2 + 7, f0 - 2, 0, 7, 7 * 20, edge);
    __syncthreads();
    conv1_panel(X4, P, wt, b1, wave, lane, t0, f0, 14, 8, edge);
    __syncthreads();
    conv_panel<22, 20, 3168, 6400>(P, Y2, wt + 1024, b2, wave, lane,
                                   t0 - 2 + 14, f0 - 2, 0, 14, 6 * 20, edge);
    __syncthreads();

    // ---- conv3/conv4 streamed in halves ----
    //   s0: Y3 storage rows [0,10) -> P ; conv4 out rows [0,8)   (lbase=0)
    //   s1: Y3 storage rows [7,18) -> P ; conv4 out rows [8,16)  (lbase=8-7=1)
    conv_panel<20, 18, 6400, 3168>(Y2, P, wt + 10240, b3, wave, lane,
                                   t0 - 1 + 0, f0 - 1, 0, 0, 10 * 18, edge);
    __syncthreads();
    conv4_panel(P, wt, b4, out, wave, lane, b, t0, f0, 0, 0);
    __syncthreads();
    conv_panel<20, 18, 6400, 3168>(Y2, P, wt + 10240, b3, wave, lane,
                                   t0 - 1 + 7, f0 - 1, 7, 0, 11 * 18, edge);
    __syncthreads();
    conv4_panel(P, wt, b4, out, wave, lane, b, t0, f0, 8, 1);
}

extern "C" void kernel_launch(void* const* d_in, const int* in_sizes, int n_in,
                              void* d_out, int out_size, void* d_ws, size_t ws_size,
                              hipStream_t stream) {
    const float* pr    = (const float*)d_in[0];
    const float* onset = (const float*)d_in[1];
    const int*   tf    = (const int*)d_in[2];
    const float* W1 = (const float*)d_in[3];
    const float* B1 = (const float*)d_in[4];
    const float* W2 = (const float*)d_in[5];
    const float* B2 = (const float*)d_in[6];
    const float* W3 = (const float*)d_in[7];
    const float* B3 = (const float*)d_in[8];
    const float* W4 = (const float*)d_in[9];
    const float* B4 = (const float*)d_in[10];
    float* out = (float*)d_out;
    unsigned short* wt = (unsigned short*)d_ws;

    prep_weights_kernel<<<32, 256, 0, stream>>>(W1, W2, W3, W4, wt);

    dim3 grid(8, 128, 8);
    fused_mfma_kernel<<<grid, 512, 0, stream>>>(pr, onset, tf, B1, B2, B3, B4, wt, out);
}

// Round 9
// 1271.306 us; speedup vs baseline: 1.2187x; 1.2187x over previous
//
#include <hip/hip_runtime.h>
#include <hip/hip_bf16.h>

#define TDIM 2048
#define FDIM 128
#define NWAVES 8

typedef __attribute__((ext_vector_type(8))) short short8;
typedef __attribute__((ext_vector_type(4))) float f32x4;
typedef __attribute__((ext_vector_type(4))) unsigned uint4v;

__device__ __forceinline__ unsigned short f2bf(float v) {
    __bf16 h = (__bf16)v;
    return __builtin_bit_cast(unsigned short, h);
}

// ---------------- weight prep -> bf16 in d_ws ----------------
//  wt1 @ 0     : [2 cot][4 kb][16 co][8 e]   k=kb*8+e, uv=k>>1, ch=k&1; 0 for k>=18   1024
//  wt2 @ 1024  : [4 g][9 uv][32 co][8 ci]                                             9216
//  wt3 @ 10240 : [4 g][9 uv][32 co][8 ci]                                             9216
//  wt4 @ 19456 : [4 g][9 uv][16 co][8 ci]  (co>0 zero)                                4608
__global__ void prep_weights_kernel(const float* __restrict__ W1, const float* __restrict__ W2,
                                    const float* __restrict__ W3, const float* __restrict__ W4,
                                    unsigned short* __restrict__ wt)
{
    for (int e = blockIdx.x * 256 + threadIdx.x; e < 24064; e += gridDim.x * 256) {
        float v = 0.0f;
        if (e < 1024) {
            int cot = e >> 9, kb = (e >> 7) & 3, co16 = (e >> 3) & 15, ee = e & 7;
            int k = kb * 8 + ee, uv = k >> 1, ch = k & 1, co = cot * 16 + co16;
            if (uv < 9) v = W1[co * 18 + ch * 9 + uv];
        } else if (e < 10240) {
            int q = e - 1024;
            int g = q / 2304, r = q % 2304;
            int uv = r >> 8, co = (r >> 3) & 31, ci = g * 8 + (r & 7);
            v = W2[co * 288 + ci * 9 + uv];
        } else if (e < 19456) {
            int q = e - 10240;
            int g = q / 2304, r = q % 2304;
            int uv = r >> 8, co = (r >> 3) & 31, ci = g * 8 + (r & 7);
            v = W3[co * 288 + ci * 9 + uv];
        } else {
            int q = e - 19456;
            int g = q / 1152, r = q % 1152;
            int uv = r >> 7, co = (r >> 3) & 15, ci = g * 8 + (r & 7);
            if (co == 0) v = W4[ci * 9 + uv];
        }
        wt[e] = f2bf(v);
    }
}

__device__ __forceinline__ uint2 pack4(f32x4 c, bool valid) {
    unsigned short h[4];
#pragma unroll
    for (int k = 0; k < 4; ++k) {
        float v = fmaxf(c[k], 0.0f);
        h[k] = valid ? f2bf(v) : (unsigned short)0;
    }
    uint2 r;
    r.x = (unsigned)h[0] | ((unsigned)h[1] << 16);
    r.y = (unsigned)h[2] | ((unsigned)h[3] << 16);
    return r;
}

// Generic panel conv: in planes [4][.. WI cols][16B] -> out planes [4][.. WO cols][16B]
// weights from global: [4 g][9 uv][32 co][8 ci]
// in row  = in_off  + r (+u);  out row = out_off + r;  r = local row index over npx=WO*nrows
template<int WI, int WO, int PSI, int PSO>
__device__ __forceinline__ void conv_panel(const char* __restrict__ inb, char* __restrict__ outb,
                                           const unsigned short* __restrict__ wg,
                                           const float* __restrict__ bias,
                                           int wave, int lane, int tvb, int f_base,
                                           int in_off, int out_off, int npx, bool edge)
{
    const int lm = lane & 15, g = lane >> 4;
    const unsigned short* wp = wg + g * 2304 + lm * 8;
    short8 wa0[9], wa1[9];
#pragma unroll
    for (int uv = 0; uv < 9; ++uv) {
        wa0[uv] = *(const short8*)(wp + uv * 256);
        wa1[uv] = *(const short8*)(wp + uv * 256 + 128);
    }
    f32x4 bias0 = *(const f32x4*)(bias + g * 4);
    f32x4 bias1 = *(const f32x4*)(bias + 16 + g * 4);
    const f32x4 zero = {0.0f, 0.0f, 0.0f, 0.0f};

    const char* inp = inb + g * PSI;
    const int NG = (npx + 15) >> 4;
    for (int grp = wave; grp < NG; grp += NWAVES) {
        int m = grp * 16 + lm;
        bool mv = m < npx;
        int mc = mv ? m : npx - 1;
        int r = mc / WO, j = mc - r * WO;
        const char* base = inp + ((in_off + r) * WI + j) * 16;
        f32x4 c0a = bias0, c0b = zero, c1a = bias1, c1b = zero;
#pragma unroll
        for (int uv = 0; uv < 9; ++uv) {
            int u = uv / 3, v = uv - u * 3;
            short8 bf = *(const short8*)(base + (u * WI + v) * 16);
            if (uv < 5) {
                c0a = __builtin_amdgcn_mfma_f32_16x16x32_bf16(wa0[uv], bf, c0a, 0, 0, 0);
                c1a = __builtin_amdgcn_mfma_f32_16x16x32_bf16(wa1[uv], bf, c1a, 0, 0, 0);
            } else {
                c0b = __builtin_amdgcn_mfma_f32_16x16x32_bf16(wa0[uv], bf, c0b, 0, 0, 0);
                c1b = __builtin_amdgcn_mfma_f32_16x16x32_bf16(wa1[uv], bf, c1b, 0, 0, 0);
            }
        }
        if (mv) {
            char* wb = outb + (g >> 1) * PSO + ((out_off + r) * WO + j) * 16 + (g & 1) * 8;
            if (edge) {
                int t = tvb + r, f = f_base + j;
                bool valid = (t >= 0) && (t < TDIM) && (f >= 0) && (f < FDIM);
                *(uint2*)wb             = pack4(c0a + c0b, valid);
                *(uint2*)(wb + 2 * PSO) = pack4(c1a + c1b, valid);
            } else {
                *(uint2*)wb             = pack4(c0a + c0b, true);
                *(uint2*)(wb + 2 * PSO) = pack4(c1a + c1b, true);
            }
        }
    }
}

// conv1 panel: X4 [24x24 px][4B] -> P planes [4][9*22][16B] (plane stride 3168)
// Y1 storage row gi = obase + i_local; K=32 packed (k=uv*2+ch)
__device__ __forceinline__ void conv1_panel(const unsigned* __restrict__ X4, char* __restrict__ P,
                                            const unsigned short* __restrict__ wt,
                                            const float* __restrict__ b1,
                                            int wave, int lane, int t0, int f0,
                                            int obase, int nrows, bool edge)
{
    const int lm = lane & 15, g = lane >> 4;
    const char* wtb = (const char*)wt;
    const short8 waA = *(const short8*)(wtb + (g * 16 + lm) * 16);
    const short8 waB = *(const short8*)(wtb + (64 + g * 16 + lm) * 16);
    int off4[4];
#pragma unroll
    for (int q = 0; q < 4; ++q) {
        int uv = g * 4 + q;
        int uvc = uv <= 8 ? uv : 8;      // weights zero beyond uv=8; clamp address only
        int u = uvc / 3, v = uvc - u * 3;
        off4[q] = u * 24 + v;
    }
    f32x4 bias0 = *(const f32x4*)(b1 + g * 4);
    f32x4 bias1 = *(const f32x4*)(b1 + 16 + g * 4);

    const int npx = nrows * 22;
    const int NG = (npx + 15) >> 4;
    for (int grp = wave; grp < NG; grp += NWAVES) {
        int m = grp * 16 + lm;
        bool mv = m < npx;
        int mc = mv ? m : npx - 1;
        int i = mc / 22, j = mc - i * 22;
        int gi = obase + i;
        int base4 = gi * 24 + j;
        uint4v bu;
#pragma unroll
        for (int q = 0; q < 4; ++q) bu[q] = X4[base4 + off4[q]];
        short8 bf = __builtin_bit_cast(short8, bu);
        f32x4 c0 = __builtin_amdgcn_mfma_f32_16x16x32_bf16(waA, bf, bias0, 0, 0, 0);
        f32x4 c1 = __builtin_amdgcn_mfma_f32_16x16x32_bf16(waB, bf, bias1, 0, 0, 0);
        if (mv) {
            char* wb = P + (g >> 1) * 3168 + (i * 22 + j) * 16 + (g & 1) * 8;
            if (edge) {
                int t = t0 - 3 + gi, f = f0 - 3 + j;
                bool valid = (t >= 0) && (t < TDIM) && (f >= 0) && (f < FDIM);
                *(uint2*)wb          = pack4(c0, valid);
                *(uint2*)(wb + 6336) = pack4(c1, valid);
            } else {
                *(uint2*)wb          = pack4(c0, true);
                *(uint2*)(wb + 6336) = pack4(c1, true);
            }
        }
    }
}

// conv4 panel: P = Y3 panel planes [4][..18 cols][16B] (plane stride 3168) -> out fp32
// out row = t0 + obase + grp; local Y3 row = lbase + grp + u
__device__ __forceinline__ void conv4_panel(const char* __restrict__ P,
                                            const unsigned short* __restrict__ wt,
                                            const float* __restrict__ b4, float* __restrict__ out,
                                            int wave, int lane, int b, int t0, int f0,
                                            int obase, int lbase)
{
    const int lm = lane & 15, g = lane >> 4;
    const unsigned short* wp = wt + 19456 + g * 1152 + lm * 8;
    short8 wa[9];
#pragma unroll
    for (int uv = 0; uv < 9; ++uv)
        wa[uv] = *(const short8*)(wp + uv * 128);
    float bv = b4[0];
    const char* yp = P + g * 3168;
    const f32x4 zero = {0.0f, 0.0f, 0.0f, 0.0f};
    for (int grp = wave; grp < 8; grp += NWAVES) {
        const char* base = yp + ((lbase + grp) * 18 + lm) * 16;
        f32x4 ca = zero, cb = zero;
#pragma unroll
        for (int uv = 0; uv < 9; ++uv) {
            int u = uv / 3, v = uv - u * 3;
            short8 bf = *(const short8*)(base + (u * 18 + v) * 16);
            if (uv < 5) ca = __builtin_amdgcn_mfma_f32_16x16x32_bf16(wa[uv], bf, ca, 0, 0, 0);
            else        cb = __builtin_amdgcn_mfma_f32_16x16x32_bf16(wa[uv], bf, cb, 0, 0, 0);
        }
        if (g == 0)
            out[((long)b * TDIM + (t0 + obase + grp)) * FDIM + f0 + lm] = ca[0] + cb[0] + bv;
    }
}

// LDS (bytes), total 40576:
//  X4 [0, 2304)      : [576 px][4B]      live through conv1 sub-phase c
//  Y2 [2304, 27904)  : planes [4][400][16]
//  P  [27904, 40576) : 12672B shared panel: Y1 thirds [4][9*22][16] / Y3 halves [4][11*18][16]
// launch_bounds(512, 6): VGPR cap ~85 (no spill; R8's (512,8)=64-cap spilled to scratch,
// 6.6 GB/dispatch HBM traffic). 6 waves/SIMD = 3 blocks/CU.
__global__ __launch_bounds__(512, 6)
void fused_mfma_kernel(const float* __restrict__ pr, const float* __restrict__ onset,
                       const int* __restrict__ tf,
                       const float* __restrict__ b1, const float* __restrict__ b2,
                       const float* __restrict__ b3, const float* __restrict__ b4,
                       const unsigned short* __restrict__ wt, float* __restrict__ out)
{
    __shared__ __attribute__((aligned(16))) char lds[40576];

    const int tid = threadIdx.x;
    const int lane = tid & 63, wave = tid >> 6;
    const int f0 = blockIdx.x * 16;
    const int t0 = blockIdx.y * 16;
    const int b  = blockIdx.z;
    const bool edge = (blockIdx.x == 0) || (blockIdx.x == 7) ||
                      (blockIdx.y == 0) || (blockIdx.y == 127);

    unsigned* X4 = (unsigned*)lds;
    char* Y2 = lds + 2304;
    char* P  = lds + 27904;

    // ---- stage X4 [24][24] with per-pixel branchless tatum search ----
    for (int p = tid; p < 576; p += 512) {
        int i = p / 24, j = p - (p / 24) * 24;
        int t = t0 - 4 + i, f = f0 - 4 + j;
        unsigned xv = 0u;
        bool valid = true;
        if (edge) valid = (t >= 0) && (t < TDIM) && (f >= 0) && (f < FDIM);
        if (valid) {
            const int* a = tf + b * 257 + 1;
            int pos = 0;
#pragma unroll
            for (int step = 128; step >= 1; step >>= 1) {
                pos += (a[pos + step - 1] <= t) ? step : 0;   // max idx 254
            }
            int idx = pos < 255 ? pos : 255;
            float v0 = pr[(b * 256 + idx) * 128 + f];
            float v1 = onset[b * 256 + idx];
            xv = (unsigned)f2bf(v0) | ((unsigned)f2bf(v1) << 16);
        }
        X4[p] = xv;
    }
    __syncthreads();

    // ---- conv1/conv2 streamed in thirds over t-rows ----
    //   s0: c1o=0  c1n=9  | c2o=0  c2n=7
    //   s1: c1o=7  c1n=9  | c2o=7  c2n=7
    //   s2: c1o=14 c1n=8  | c2o=14 c2n=6
    conv1_panel(X4, P, wt, b1, wave, lane, t0, f0, 0, 9, edge);
    __syncthreads();
    conv_panel<22, 20, 3168, 6400>(P, Y2, wt + 1024, b2, wave, lane,
                                   t0 - 2 + 0, f0 - 2, 0, 0, 7 * 20, edge);
    __syncthreads();
    conv1_panel(X4, P, wt, b1, wave, lane, t0, f0, 7, 9, edge);
    __syncthreads();
    conv_panel<22, 20, 3168, 6400>(P, Y2, wt + 1024, b2, wave, lane,
                                   t0 - 2 + 7, f0 - 2, 0, 7, 7 * 20, edge);
    __syncthreads();
    conv1_panel(X4, P, wt, b1, wave, lane, t0, f0, 14, 8, edge);
    __syncthreads();
    conv_panel<22, 20, 3168, 6400>(P, Y2, wt + 1024, b2, wave, lane,
                                   t0 - 2 + 14, f0 - 2, 0, 14, 6 * 20, edge);
    __syncthreads();

    // ---- conv3/conv4 streamed in halves ----
    //   s0: Y3 storage rows [0,10) -> P ; conv4 out rows [0,8)   (lbase=0)
    //   s1: Y3 storage rows [7,18) -> P ; conv4 out rows [8,16)  (lbase=1)
    conv_panel<20, 18, 6400, 3168>(Y2, P, wt + 10240, b3, wave, lane,
                                   t0 - 1 + 0, f0 - 1, 0, 0, 10 * 18, edge);
    __syncthreads();
    conv4_panel(P, wt, b4, out, wave, lane, b, t0, f0, 0, 0);
    __syncthreads();
    conv_panel<20, 18, 6400, 3168>(Y2, P, wt + 10240, b3, wave, lane,
                                   t0 - 1 + 7, f0 - 1, 7, 0, 11 * 18, edge);
    __syncthreads();
    conv4_panel(P, wt, b4, out, wave, lane, b, t0, f0, 8, 1);
}

extern "C" void kernel_launch(void* const* d_in, const int* in_sizes, int n_in,
                              void* d_out, int out_size, void* d_ws, size_t ws_size,
                              hipStream_t stream) {
    const float* pr    = (const float*)d_in[0];
    const float* onset = (const float*)d_in[1];
    const int*   tf    = (const int*)d_in[2];
    const float* W1 = (const float*)d_in[3];
    const float* B1 = (const float*)d_in[4];
    const float* W2 = (const float*)d_in[5];
    const float* B2 = (const float*)d_in[6];
    const float* W3 = (const float*)d_in[7];
    const float* B3 = (const float*)d_in[8];
    const float* W4 = (const float*)d_in[9];
    const float* B4 = (const float*)d_in[10];
    float* out = (float*)d_out;
    unsigned short* wt = (unsigned short*)d_ws;

    prep_weights_kernel<<<32, 256, 0, stream>>>(W1, W2, W3, W4, wt);

    dim3 grid(8, 128, 8);
    fused_mfma_kernel<<<grid, 512, 0, stream>>>(pr, onset, tf, B1, B2, B3, B4, wt, out);
}